// Round 13
// baseline (205.957 us; speedup 1.0000x reference)
//
#include <hip/hip_runtime.h>
#include <math.h>

// Problem constants
#define B_  4
#define S_  1024
#define D_  1024
#define H_  16
#define DK_ 64
#define M_  (B_ * S_)

typedef __bf16 bf16x8 __attribute__((ext_vector_type(8)));
typedef float  f32x4  __attribute__((ext_vector_type(4)));

// ---- bf16 helpers (RNE) ----------------------------------------------------
__device__ __forceinline__ unsigned short f2bf(float f) {
  unsigned u = __builtin_bit_cast(unsigned, f);
  u = (u + 0x7FFFu + ((u >> 16) & 1u)) >> 16;
  return (unsigned short)u;
}
__device__ __forceinline__ float bf2f(unsigned short h) {
  unsigned u = ((unsigned)h) << 16;
  return __builtin_bit_cast(float, u);
}

// async global->LDS, 16 B per lane; LDS dest = wave-uniform base + lane*16
__device__ __forceinline__ void gl_lds16(const void* g, void* lds) {
  __builtin_amdgcn_global_load_lds(
      (const __attribute__((address_space(1))) unsigned int*)(unsigned long long)g,
      (__attribute__((address_space(3))) unsigned int*)(unsigned int)(unsigned long long)lds,
      16, 0, 0);
}

// ---------------------------------------------------------------------------
// PREP (one kernel, branch by blockIdx):
//  [0,2048):     X fp32 -> bf16 cast (8 elems/thread)
//  [2048,2560):  W_G fp32 -> bf16 cast, layout preserved (WGbf)  [NEW: no
//                transpose needed — W_G serves as BT in the small GEMM]
//  [2560,3584):  Wk transpose+cast -> WkT bf16 [n][k]
//  [3584,3712):  RoPE table
//  [3712,3716):  bias_k[n] = b_G @ Wk[:,n] + bk[n]  (coalesced row-walk)
//  [3716,3780):  gr0[b][n] = x[b,0,:]@W_G + b_G  (fp32 GEMV, round-9 proven)
// ---------------------------------------------------------------------------
__global__ __launch_bounds__(256) void prep_kernel(
    const float* __restrict__ X, const float* __restrict__ W_G,
    const float* __restrict__ Wk, const float* __restrict__ b_G,
    const float* __restrict__ bk, unsigned short* __restrict__ Xbf,
    unsigned short* __restrict__ WGbf, unsigned short* __restrict__ WkT,
    float* __restrict__ tab, float* __restrict__ biask,
    float* __restrict__ gr0) {
  __shared__ float tle[32][33];
  __shared__ float xs[1024];
  __shared__ float pall[256];
  const int blk = blockIdx.x;
  const int tid = threadIdx.x;

  if (blk < 2048) {
    const int i = (blk * 256 + tid) * 2;  // float4 index
    const float4 v0 = ((const float4*)X)[i];
    const float4 v1 = ((const float4*)X)[i + 1];
    ushort4 h0, h1;
    h0.x = f2bf(v0.x); h0.y = f2bf(v0.y); h0.z = f2bf(v0.z); h0.w = f2bf(v0.w);
    h1.x = f2bf(v1.x); h1.y = f2bf(v1.y); h1.z = f2bf(v1.z); h1.w = f2bf(v1.w);
    ((ushort4*)Xbf)[i] = h0;
    ((ushort4*)Xbf)[i + 1] = h1;
  } else if (blk < 2560) {
    const int i = ((blk - 2048) * 256 + tid) * 2;
    const float4 v0 = ((const float4*)W_G)[i];
    const float4 v1 = ((const float4*)W_G)[i + 1];
    ushort4 h0, h1;
    h0.x = f2bf(v0.x); h0.y = f2bf(v0.y); h0.z = f2bf(v0.z); h0.w = f2bf(v0.w);
    h1.x = f2bf(v1.x); h1.y = f2bf(v1.y); h1.z = f2bf(v1.z); h1.w = f2bf(v1.w);
    ((ushort4*)WGbf)[i] = h0;
    ((ushort4*)WGbf)[i + 1] = h1;
  } else if (blk < 3584) {
    const int t = blk - 2560;
    const int k0 = (t & 31) * 32;
    const int n0 = (t >> 5) * 32;
    const int tx = tid & 31;
    const int ty = tid >> 5;  // 0..7
#pragma unroll
    for (int r = 0; r < 32; r += 8)
      tle[ty + r][tx] = Wk[(size_t)(k0 + ty + r) * 1024 + n0 + tx];
    __syncthreads();
#pragma unroll
    for (int r = 0; r < 32; r += 8)
      WkT[(size_t)(n0 + ty + r) * 1024 + k0 + tx] = f2bf(tle[tx][ty + r]);
  } else if (blk < 3712) {
    const int idx = (blk - 3584) * 256 + tid;
    const int s = idx >> 5, j = idx & 31;
    const float inv = (float)exp(-(double)j * (9.210340371976182736 / 32.0));
    float sn, c;
    sincosf((float)s * inv, &sn, &c);
    tab[(size_t)s * 64 + 2 * j] = c;
    tab[(size_t)s * 64 + 2 * j + 1] = sn;
  } else if (blk < 3716) {
    // bias_k: each of 4 blocks handles 256 n; per k, wave reads a coalesced
    // row segment of Wk.
    const int n = (blk - 3712) * 256 + tid;
    for (int i = tid; i < 1024; i += 256) xs[i] = b_G[i];
    __syncthreads();
    float acc = bk[n];
    for (int k = 0; k < 1024; ++k)
      acc = fmaf(xs[k], Wk[(size_t)k * 1024 + n], acc);
    biask[n] = acc;
  } else {
    // gr0 GEMV unit (round-9 proven)
    const int u = blk - 3716;           // 0..63
    const int b = u >> 4;               // 0..3
    const int n0g = (u & 15) * 64;
    const int nl = tid & 63;
    const int kq = tid >> 6;            // 0..3
    for (int i = tid; i < 1024; i += 256) xs[i] = X[(size_t)b * S_ * D_ + i];
    __syncthreads();
    float acc = 0.f;
    const int ks = kq * 256;
    for (int k = ks; k < ks + 256; ++k)
      acc = fmaf(xs[k], W_G[(size_t)k * 1024 + n0g + nl], acc);
    pall[tid] = acc;
    __syncthreads();
    if (tid < 64)
      gr0[(size_t)b * 1024 + n0g + tid] = pall[tid] + pall[64 + tid] +
                                          pall[128 + tid] + pall[192 + tid] +
                                          b_G[n0g + tid];
  }
}

// ---------------------------------------------------------------------------
// bf16 MFMA GEMM (proven inner loop + XCD-aware decode, now shape-generic):
// C[m][n] = bf16( sum_k A[m][k]*BT[n][k] + (bias?bias[n]:0) ).
// Decode: by = flat & mtMask (M-tiles), bx = flat >> mtShift -> XCD = by%8
// (same-A-panel blocks share an XCD when M-tiles is a multiple of 8).
// Blocks >= nGemmBlocks run the q0 split-K partials from gr0 (fp32).
// ---------------------------------------------------------------------------
#define GM 64
#define GN 128

__global__ __launch_bounds__(256) void gemm_bf16(
    const unsigned short* __restrict__ A, const unsigned short* __restrict__ BT,
    const float* __restrict__ bias, unsigned short* __restrict__ C,
    const float* __restrict__ gr0, const float* __restrict__ Wq,
    float* __restrict__ part, int nGemmBlocks, int mtMask, int mtShift) {
  __shared__ __align__(16) unsigned short As[2][GM * 32];   // 8 KB
  __shared__ __align__(16) unsigned short Bs[2][GN * 32];   // 16 KB
  __shared__ float gs[4][32];

  const int flat = blockIdx.x;
  const int tid  = threadIdx.x;

  if (flat >= nGemmBlocks) {
    // ---- q0 partial: part[(slab*4+b)*D+n] = sum_{k in slab} gr0[b,k]*Wq[k,n]
    const int qb = flat - nGemmBlocks;   // 0..127
    const int slab = qb >> 2;            // 0..31
    const int n = (qb & 3) * 256 + tid;  // 0..1023
    if (tid < 128) {
      const int b = tid >> 5, kk = tid & 31;
      gs[b][kk] = gr0[(size_t)b * 1024 + slab * 32 + kk];
    }
    __syncthreads();
    float a0 = 0.f, a1 = 0.f, a2 = 0.f, a3 = 0.f;
#pragma unroll
    for (int kk = 0; kk < 32; ++kk) {
      const float w = Wq[(size_t)(slab * 32 + kk) * D_ + n];
      a0 = fmaf(gs[0][kk], w, a0);
      a1 = fmaf(gs[1][kk], w, a1);
      a2 = fmaf(gs[2][kk], w, a2);
      a3 = fmaf(gs[3][kk], w, a3);
    }
    part[(size_t)(slab * 4 + 0) * D_ + n] = a0;
    part[(size_t)(slab * 4 + 1) * D_ + n] = a1;
    part[(size_t)(slab * 4 + 2) * D_ + n] = a2;
    part[(size_t)(slab * 4 + 3) * D_ + n] = a3;
    return;
  }

  // ---- GEMM path (XCD-aware decode, shape-generic) ----
  const int bx = flat >> mtShift;
  const int by = flat & mtMask;
  const int wv   = tid >> 6;
  const int lane = tid & 63;
  const int m0 = by * GM;
  const int n0 = bx * GN;

  const int colOff = (lane & 3) * 8;
  const size_t aOff  = (size_t)(m0 + 16 * wv + (lane >> 2)) * 1024 + colOff;
  const size_t bOff0 = (size_t)(n0 + 32 * wv + (lane >> 2)) * 1024 + colOff;
  const size_t bOff1 = bOff0 + (size_t)16 * 1024;

  const int l15  = lane & 15;
  const int quad = lane >> 4;

  f32x4 acc[4][2];
#pragma unroll
  for (int i = 0; i < 4; ++i)
#pragma unroll
    for (int j = 0; j < 2; ++j) acc[i][j] = (f32x4){0.f, 0.f, 0.f, 0.f};

#pragma unroll 1
  for (int k0 = 0; k0 < 1024; k0 += 64) {
    __syncthreads();                      // prior LDS reads done
#pragma unroll
    for (int ks = 0; ks < 2; ++ks) {
      gl_lds16(A  + aOff  + k0 + ks * 32, &As[ks][wv * 512]);
      gl_lds16(BT + bOff0 + k0 + ks * 32, &Bs[ks][wv * 1024]);
      gl_lds16(BT + bOff1 + k0 + ks * 32, &Bs[ks][wv * 1024 + 512]);
    }
    __syncthreads();                      // vmcnt drain: LDS writes visible

#pragma unroll
    for (int ks = 0; ks < 2; ++ks) {
      bf16x8 af[4], bfr[2];
#pragma unroll
      for (int mi = 0; mi < 4; ++mi)
        af[mi] = *(const bf16x8*)(&As[ks][(mi * 16 + l15) * 32 + quad * 8]);
#pragma unroll
      for (int ni = 0; ni < 2; ++ni)
        bfr[ni] =
            *(const bf16x8*)(&Bs[ks][(wv * 32 + ni * 16 + l15) * 32 + quad * 8]);
#pragma unroll
      for (int mi = 0; mi < 4; ++mi)
#pragma unroll
        for (int ni = 0; ni < 2; ++ni)
          acc[mi][ni] = __builtin_amdgcn_mfma_f32_16x16x32_bf16(
              af[mi], bfr[ni], acc[mi][ni], 0, 0, 0);
    }
  }

  // epilogue: C/D layout col = lane&15, row = quad*4 + r (m89/m91 verified)
#pragma unroll
  for (int ni = 0; ni < 2; ++ni) {
    const int n = n0 + wv * 32 + ni * 16 + l15;
    const float bv = bias ? bias[n] : 0.f;
#pragma unroll
    for (int mi = 0; mi < 4; ++mi) {
#pragma unroll
      for (int r = 0; r < 4; ++r) {
        const int m = m0 + mi * 16 + quad * 4 + r;
        C[(size_t)m * 1024 + n] = f2bf(acc[mi][ni][r] + bv);
      }
    }
  }
}

// ---------------------------------------------------------------------------
// Attention row-0 scores (round-6 verbatim).
// ---------------------------------------------------------------------------
__global__ __launch_bounds__(256) void attn_scores_kernel(
    const unsigned short* __restrict__ Kbf, const float* __restrict__ part,
    const float* __restrict__ bq, const float* __restrict__ tab,
    const int* __restrict__ mask, float* __restrict__ scores,
    float* __restrict__ mS) {
  const int bi = blockIdx.x;
  const int b = bi >> 9;
  const int h = (bi >> 5) & 15;
  const int chunk = bi & 31;
  const int tid = threadIdx.x;
  const int bh = b * H_ + h;
  const int sl = tid >> 3;  // 0..31
  const int j  = tid & 7;   // 16B chunk within the 64-elem row
  const int s  = chunk * 32 + sl;

  __shared__ float q0s[DK_];
  __shared__ float wredm[4];
  __shared__ float wreds[4];

  if (tid < 64) {
    const int n = h * DK_ + tid;
    float v = bq[n];
#pragma unroll
    for (int sl2 = 0; sl2 < 32; ++sl2)
      v += part[(size_t)(sl2 * 4 + b) * D_ + n];
    q0s[tid] = v;
  }
  __syncthreads();

  const ushort4* kp =
      (const ushort4*)(Kbf + ((size_t)(b * S_ + s)) * D_ + h * DK_ + j * 8);
  const ushort4 k0 = kp[0], k1 = kp[1];
  const float4* tb = (const float4*)(tab + (size_t)s * 64 + j * 8);
  const float4 t0 = tb[0], t1 = tb[1];

  float dot = 0.f;
  {
    const float ka = bf2f(k0.x), kb = bf2f(k0.y);
    dot += q0s[j * 8 + 0] * (ka * t0.x - kb * t0.y) +
           q0s[j * 8 + 1] * (kb * t0.x + ka * t0.y);
  }
  {
    const float ka = bf2f(k0.z), kb = bf2f(k0.w);
    dot += q0s[j * 8 + 2] * (ka * t0.z - kb * t0.w) +
           q0s[j * 8 + 3] * (kb * t0.z + ka * t0.w);
  }
  {
    const float ka = bf2f(k1.x), kb = bf2f(k1.y);
    dot += q0s[j * 8 + 4] * (ka * t1.x - kb * t1.y) +
           q0s[j * 8 + 5] * (kb * t1.x + ka * t1.y);
  }
  {
    const float ka = bf2f(k1.z), kb = bf2f(k1.w);
    dot += q0s[j * 8 + 6] * (ka * t1.z - kb * t1.w) +
           q0s[j * 8 + 7] * (kb * t1.z + ka * t1.w);
  }
  dot += __shfl_xor(dot, 1);
  dot += __shfl_xor(dot, 2);
  dot += __shfl_xor(dot, 4);
  dot *= 0.125f;  // 1/sqrt(64)
  if (mask[b * S_ + s] == 0) dot = -1e9f;
  if (j == 0) scores[(size_t)bh * S_ + s] = dot;

  float mx = dot;
#pragma unroll
  for (int off = 8; off < 64; off <<= 1) mx = fmaxf(mx, __shfl_xor(mx, off));
  if ((tid & 63) == 0) wredm[tid >> 6] = mx;
  __syncthreads();
  mx = fmaxf(fmaxf(wredm[0], wredm[1]), fmaxf(wredm[2], wredm[3]));

  float e = (j == 0) ? expf(dot - mx) : 0.f;
#pragma unroll
  for (int off = 1; off < 64; off <<= 1) e += __shfl_xor(e, off);
  if ((tid & 63) == 0) wreds[tid >> 6] = e;
  __syncthreads();
  if (tid == 0) {
    mS[(size_t)(bh * 32 + chunk) * 2 + 0] = mx;
    mS[(size_t)(bh * 32 + chunk) * 2 + 1] =
        wreds[0] + wreds[1] + wreds[2] + wreds[3];
  }
}

// ---------------------------------------------------------------------------
// Conv1d + bias + ReLU, register-tiled 8x8 (round-12 v3 verbatim).
// ---------------------------------------------------------------------------
__global__ __launch_bounds__(256) void conv_norm_relu_kernel(
    const float* __restrict__ scores, const float* __restrict__ mS,
    const float* __restrict__ cw, const float* __restrict__ cb,
    float* __restrict__ out) {
  const int b  = blockIdx.y;
  const int s0 = blockIdx.x * 128;
  const int o0 = blockIdx.z * 128;
  const int tid = threadIdx.x;
  const int tx = tid & 15;   // s group
  const int ty = tid >> 4;   // o group

  __shared__ float msh[16], ish[16];
  __shared__ __align__(16) float wT[48][128];
  __shared__ float cbs[128];
  __shared__ __align__(16) float pm[16][132];

  if (tid < 16) {
    const int bh = b * H_ + tid;
    float m = -3e38f;
#pragma unroll
    for (int c = 0; c < 32; ++c)
      m = fmaxf(m, mS[(size_t)(bh * 32 + c) * 2]);
    float S = 0.f;
#pragma unroll
    for (int c = 0; c < 32; ++c)
      S += mS[(size_t)(bh * 32 + c) * 2 + 1] *
           expf(mS[(size_t)(bh * 32 + c) * 2] - m);
    msh[tid] = m;
    ish[tid] = 1.f / S;
  }
  for (int i = tid; i < 128 * 48; i += 256) {
    const int ol = i / 48, ct = i % 48;
    wT[ct][ol] = cw[(size_t)(o0 + ol) * 48 + ct];
  }
  if (tid < 128) cbs[tid] = cb[o0 + tid];
  __syncthreads();

  for (int i = tid; i < 16 * 130; i += 256) {
    const int c = i / 130, ss = i % 130;
    const int gs = s0 - 1 + ss;
    pm[c][ss] = (gs >= 0 && gs < S_)
                    ? expf(scores[(size_t)(b * H_ + c) * S_ + gs] - msh[c]) *
                          ish[c]
                    : 0.f;
  }
  __syncthreads();

  float acc[8][8];
#pragma unroll
  for (int i = 0; i < 8; ++i) {
    const float cv = cbs[ty * 8 + i];
#pragma unroll
    for (int j = 0; j < 8; ++j) acc[i][j] = cv;
  }

#pragma unroll
  for (int c = 0; c < 16; ++c) {
    float p[12];
    *(float4*)(p + 0) = *(const float4*)&pm[c][tx * 8 + 0];
    *(float4*)(p + 4) = *(const float4*)&pm[c][tx * 8 + 4];
    *(float4*)(p + 8) = *(const float4*)&pm[c][tx * 8 + 8];
#pragma unroll
    for (int t = 0; t < 3; ++t) {
      float w[8];
      *(float4*)(w + 0) = *(const float4*)&wT[c * 3 + t][ty * 8 + 0];
      *(float4*)(w + 4) = *(const float4*)&wT[c * 3 + t][ty * 8 + 4];
#pragma unroll
      for (int i = 0; i < 8; ++i)
#pragma unroll
        for (int j = 0; j < 8; ++j)
          acc[i][j] = fmaf(p[j + t], w[i], acc[i][j]);
    }
  }

#pragma unroll
  for (int i = 0; i < 8; ++i) {
    float* orow =
        out + ((size_t)b * D_ + o0 + ty * 8 + i) * S_ + s0 + tx * 8;
    float4 v0, v1;
    v0.x = fmaxf(acc[i][0], 0.f); v0.y = fmaxf(acc[i][1], 0.f);
    v0.z = fmaxf(acc[i][2], 0.f); v0.w = fmaxf(acc[i][3], 0.f);
    v1.x = fmaxf(acc[i][4], 0.f); v1.y = fmaxf(acc[i][5], 0.f);
    v1.z = fmaxf(acc[i][6], 0.f); v1.w = fmaxf(acc[i][7], 0.f);
    *(float4*)(orow + 0) = v0;
    *(float4*)(orow + 4) = v1;
  }
}

// ---------------------------------------------------------------------------
// Workspace (peak ~23.2 MB):
//  [ 0, 8M) Xbf | [8,16M) Kbf | [16,18M) WkT | [18,20M) WGbf | [20,22M) WcT
//  [22M): gr0 16K | biask 4K | part 512K | ropeT 256K | scores 256K | mS 16K
// ---------------------------------------------------------------------------
extern "C" void kernel_launch(void* const* d_in, const int* in_sizes, int n_in,
                              void* d_out, int out_size, void* d_ws,
                              size_t ws_size, hipStream_t stream) {
  const float* x    = (const float*)d_in[0];
  const int*   mask = (const int*)d_in[1];
  const float* W_G  = (const float*)d_in[2];
  const float* b_G  = (const float*)d_in[3];
  const float* Wq   = (const float*)d_in[4];
  const float* bq   = (const float*)d_in[5];
  const float* Wk   = (const float*)d_in[6];
  const float* bk   = (const float*)d_in[7];
  const float* cw   = (const float*)d_in[8];
  const float* cb   = (const float*)d_in[9];
  float* out = (float*)d_out;

  char* ws = (char*)d_ws;
  unsigned short* Xbf  = (unsigned short*)(ws);
  unsigned short* Kbf  = (unsigned short*)(ws + (8u << 20));
  unsigned short* WkT  = (unsigned short*)(ws + (16u << 20));
  unsigned short* WGbf = (unsigned short*)(ws + (18u << 20));
  unsigned short* WcT  = (unsigned short*)(ws + (20u << 20));
  char* base2 = ws + (22u << 20);
  float* gr0    = (float*)(base2);
  float* biask  = (float*)(base2 + (16u << 10));
  float* part   = (float*)(base2 + (20u << 10));
  float* ropeT  = (float*)(base2 + (532u << 10));
  float* scores = (float*)(base2 + (788u << 10));
  float* mS     = (float*)(base2 + (1044u << 10));

  prep_kernel<<<3780, 256, 0, stream>>>(x, W_G, Wk, b_G, bk, Xbf, WGbf, WkT,
                                        ropeT, biask, gr0);
  // small GEMM: WcT[n][k] = sum_j WkT[n][j]*WGbf[k][j]  (= (W_G@Wk)^T), no
  // bias; blocks >= 128 compute q0 partials from gr0.  M-tiles=16 -> mask 15.
  gemm_bf16<<<256, 256, 0, stream>>>(WkT, WGbf, nullptr, WcT, gr0, Wq, part,
                                     128, 15, 4);
  // big GEMM: Kbf = bf16(Xbf @ W_comb + bias_k).  M-tiles=64 -> mask 63.
  gemm_bf16<<<512, 256, 0, stream>>>(Xbf, WcT, biask, Kbf, nullptr, nullptr,
                                     nullptr, 512, 63, 6);
  attn_scores_kernel<<<2048, 256, 0, stream>>>(Kbf, part, bq, ropeT, mask,
                                               scores, mS);
  conv_norm_relu_kernel<<<dim3(8, B_, 8), 256, 0, stream>>>(
      scores, mS, cw, cb, out);
}